// Round 1
// baseline (4618.488 us; speedup 1.0000x reference)
//
#include <hip/hip_runtime.h>

#define NN 100000
#define NE 1000000
#define DD 64

// ---------------------------------------------------------------- deg count
__global__ __launch_bounds__(256) void k_count(const int* __restrict__ tgt,
                                               float* __restrict__ deg) {
    int i = blockIdx.x * blockDim.x + threadIdx.x;
    if (i < NE) atomicAdd(&deg[tgt[i]], 1.0f);
}

// ------------------------------------------------- message matvec + scatter
// per edge: m = relu(W^T cat(x[src], ea[e]) + b); atomicAdd into agg[tgt]
__global__ __launch_bounds__(256, 2) void k_msg(
    const float* __restrict__ x, const float* __restrict__ ea,
    const int* __restrict__ ei,
    const float* __restrict__ W, const float* __restrict__ bias,
    float* __restrict__ agg)
{
    __shared__ __attribute__((aligned(16))) float sIn[4][4][128];
    const int lane = threadIdx.x & 63;
    const int wv   = threadIdx.x >> 6;

    float w[128];
#pragma unroll
    for (int k = 0; k < 128; ++k) w[k] = W[k * DD + lane];
    const float bl = bias[lane];

    const int wt    = (gridDim.x * blockDim.x) >> 6;
    const int wid   = (blockIdx.x * blockDim.x + threadIdx.x) >> 6;
    const int niter = (NE + wt * 4 - 1) / (wt * 4);

    for (int it = 0; it < niter; ++it) {
        const int e0 = (it * wt + wid) * 4;
#pragma unroll
        for (int s = 0; s < 4; ++s) {
            const int e = e0 + s;
            float vx = 0.f, ve = 0.f;
            if (e < NE) {
                const int sn = ei[e];
                vx = x[sn * DD + lane];
                ve = ea[e * DD + lane];
            }
            sIn[wv][s][lane]      = vx;
            sIn[wv][s][64 + lane] = ve;
        }
        __syncthreads();
#pragma unroll 1
        for (int s = 0; s < 4; ++s) {
            const int e = e0 + s;
            const float4* in4 = (const float4*)(&sIn[wv][s][0]);
            float a0 = 0.f, a1 = 0.f, a2 = 0.f, a3 = 0.f;
#pragma unroll
            for (int k = 0; k < 32; ++k) {
                const float4 v = in4[k];
                a0 = fmaf(v.x, w[4 * k + 0], a0);
                a1 = fmaf(v.y, w[4 * k + 1], a1);
                a2 = fmaf(v.z, w[4 * k + 2], a2);
                a3 = fmaf(v.w, w[4 * k + 3], a3);
            }
            const float m = fmaxf((a0 + a1) + (a2 + a3) + bl, 0.f);
            if (e < NE) {
                const int tn = ei[NE + e];
                atomicAdd(&agg[tn * DD + lane], m);
            }
        }
        __syncthreads();
    }
}

// ------------------------------------------------------------- node update
// h = relu(W^T cat(agg[n]/deg, x[n]) + b); x_out = h / max(||h||, 1e-12)
__global__ __launch_bounds__(256, 2) void k_node(
    const float* __restrict__ x, const float* __restrict__ agg,
    const float* __restrict__ deg,
    const float* __restrict__ W, const float* __restrict__ bias,
    float* __restrict__ xout)
{
    __shared__ __attribute__((aligned(16))) float sIn[4][4][128];
    const int lane = threadIdx.x & 63;
    const int wv   = threadIdx.x >> 6;

    float w[128];
#pragma unroll
    for (int k = 0; k < 128; ++k) w[k] = W[k * DD + lane];
    const float bl = bias[lane];

    const int wt    = (gridDim.x * blockDim.x) >> 6;
    const int wid   = (blockIdx.x * blockDim.x + threadIdx.x) >> 6;
    const int niter = (NN + wt * 4 - 1) / (wt * 4);

    for (int it = 0; it < niter; ++it) {
        const int n0 = (it * wt + wid) * 4;
#pragma unroll
        for (int s = 0; s < 4; ++s) {
            const int n = n0 + s;
            float va = 0.f, vx = 0.f;
            if (n < NN) {
                const float d = fmaxf(deg[n], 1.0f);
                va = agg[n * DD + lane] / d;
                vx = x[n * DD + lane];
            }
            sIn[wv][s][lane]      = va;
            sIn[wv][s][64 + lane] = vx;
        }
        __syncthreads();
#pragma unroll 1
        for (int s = 0; s < 4; ++s) {
            const int n = n0 + s;
            const float4* in4 = (const float4*)(&sIn[wv][s][0]);
            float a0 = 0.f, a1 = 0.f, a2 = 0.f, a3 = 0.f;
#pragma unroll
            for (int k = 0; k < 32; ++k) {
                const float4 v = in4[k];
                a0 = fmaf(v.x, w[4 * k + 0], a0);
                a1 = fmaf(v.y, w[4 * k + 1], a1);
                a2 = fmaf(v.z, w[4 * k + 2], a2);
                a3 = fmaf(v.w, w[4 * k + 3], a3);
            }
            float h = fmaxf((a0 + a1) + (a2 + a3) + bl, 0.f);
            // L2 norm across the 64 lanes
            float s2 = h * h;
#pragma unroll
            for (int off = 32; off > 0; off >>= 1) s2 += __shfl_xor(s2, off);
            const float nrm = fmaxf(sqrtf(s2), 1e-12f);
            if (n < NN) xout[n * DD + lane] = h / nrm;
        }
        __syncthreads();
    }
}

// ------------------------------------------------------------- edge update
// ea_out = relu(W^T cat(x[src], x[tgt], ea) + b)
__global__ __launch_bounds__(256, 2) void k_eup(
    const float* __restrict__ x, const float* __restrict__ ea,
    const int* __restrict__ ei,
    const float* __restrict__ W, const float* __restrict__ bias,
    float* __restrict__ eout)
{
    __shared__ __attribute__((aligned(16))) float sIn[4][4][192];
    const int lane = threadIdx.x & 63;
    const int wv   = threadIdx.x >> 6;

    float w[192];
#pragma unroll
    for (int k = 0; k < 192; ++k) w[k] = W[k * DD + lane];
    const float bl = bias[lane];

    const int wt    = (gridDim.x * blockDim.x) >> 6;
    const int wid   = (blockIdx.x * blockDim.x + threadIdx.x) >> 6;
    const int niter = (NE + wt * 4 - 1) / (wt * 4);

    for (int it = 0; it < niter; ++it) {
        const int e0 = (it * wt + wid) * 4;
#pragma unroll
        for (int s = 0; s < 4; ++s) {
            const int e = e0 + s;
            float vs = 0.f, vt = 0.f, ve = 0.f;
            if (e < NE) {
                const int sn = ei[e];
                const int tn = ei[NE + e];
                vs = x[sn * DD + lane];
                vt = x[tn * DD + lane];
                ve = ea[e * DD + lane];
            }
            sIn[wv][s][lane]       = vs;
            sIn[wv][s][64 + lane]  = vt;
            sIn[wv][s][128 + lane] = ve;
        }
        __syncthreads();
#pragma unroll 1
        for (int s = 0; s < 4; ++s) {
            const int e = e0 + s;
            const float4* in4 = (const float4*)(&sIn[wv][s][0]);
            float a0 = 0.f, a1 = 0.f, a2 = 0.f, a3 = 0.f;
#pragma unroll
            for (int k = 0; k < 48; ++k) {
                const float4 v = in4[k];
                a0 = fmaf(v.x, w[4 * k + 0], a0);
                a1 = fmaf(v.y, w[4 * k + 1], a1);
                a2 = fmaf(v.z, w[4 * k + 2], a2);
                a3 = fmaf(v.w, w[4 * k + 3], a3);
            }
            const float m = fmaxf((a0 + a1) + (a2 + a3) + bl, 0.f);
            if (e < NE) eout[e * DD + lane] = m;
        }
        __syncthreads();
    }
}

// ---------------------------------------------------------------- post MLP
// out = relu(x W1 + b1) W2 + b2
__global__ __launch_bounds__(256, 2) void k_post(
    const float* __restrict__ x,
    const float* __restrict__ W1, const float* __restrict__ b1,
    const float* __restrict__ W2, const float* __restrict__ b2,
    float* __restrict__ out)
{
    __shared__ __attribute__((aligned(16))) float sIn[4][4][64];
    const int lane = threadIdx.x & 63;
    const int wv   = threadIdx.x >> 6;

    float w1[64], w2[64];
#pragma unroll
    for (int k = 0; k < 64; ++k) w1[k] = W1[k * DD + lane];
#pragma unroll
    for (int k = 0; k < 64; ++k) w2[k] = W2[k * DD + lane];
    const float bl1 = b1[lane];
    const float bl2 = b2[lane];

    const int wt    = (gridDim.x * blockDim.x) >> 6;
    const int wid   = (blockIdx.x * blockDim.x + threadIdx.x) >> 6;
    const int niter = (NN + wt * 4 - 1) / (wt * 4);

    for (int it = 0; it < niter; ++it) {
        const int n0 = (it * wt + wid) * 4;
#pragma unroll
        for (int s = 0; s < 4; ++s) {
            const int n = n0 + s;
            float vx = 0.f;
            if (n < NN) vx = x[n * DD + lane];
            sIn[wv][s][lane] = vx;
        }
        __syncthreads();
#pragma unroll 1
        for (int s = 0; s < 4; ++s) {
            const int n = n0 + s;
            const float4* in4 = (const float4*)(&sIn[wv][s][0]);
            float a0 = 0.f, a1 = 0.f, a2 = 0.f, a3 = 0.f;
#pragma unroll
            for (int k = 0; k < 16; ++k) {
                const float4 v = in4[k];
                a0 = fmaf(v.x, w1[4 * k + 0], a0);
                a1 = fmaf(v.y, w1[4 * k + 1], a1);
                a2 = fmaf(v.z, w1[4 * k + 2], a2);
                a3 = fmaf(v.w, w1[4 * k + 3], a3);
            }
            const float h = fmaxf((a0 + a1) + (a2 + a3) + bl1, 0.f);
            // second matvec: broadcast h across lanes via shfl
            float acc = bl2;
#pragma unroll
            for (int k = 0; k < 64; ++k) acc = fmaf(__shfl(h, k), w2[k], acc);
            if (n < NN) out[n * DD + lane] = acc;
        }
        __syncthreads();
    }
}

// --------------------------------------------------------------------------
extern "C" void kernel_launch(void* const* d_in, const int* in_sizes, int n_in,
                              void* d_out, int out_size, void* d_ws, size_t ws_size,
                              hipStream_t stream)
{
    const float* x_in  = (const float*)d_in[0];
    const float* ea_in = (const float*)d_in[1];
    const int*   ei    = (const int*)d_in[2];
    const float* msg_W = (const float*)d_in[3];
    const float* msg_b = (const float*)d_in[4];
    const float* agg_W = (const float*)d_in[5];
    const float* agg_b = (const float*)d_in[6];
    const float* eup_W = (const float*)d_in[7];
    const float* eup_b = (const float*)d_in[8];
    const float* pW1   = (const float*)d_in[9];
    const float* pb1   = (const float*)d_in[10];
    const float* pW2   = (const float*)d_in[11];
    const float* pb2   = (const float*)d_in[12];
    float* out = (float*)d_out;

    float* deg = (float*)d_ws;                 // NN (padded to 100352)
    float* agg = deg + 100352;                 // NN*DD
    float* eab = agg + NN * DD;                // NE*DD
    float* xb  = out;                          // reuse d_out as x buffer

    hipMemsetAsync(deg, 0, NN * sizeof(float), stream);
    k_count<<<(NE + 255) / 256, 256, 0, stream>>>(ei + NE, deg);

    for (int l = 0; l < 3; ++l) {
        const float* xc = (l == 0) ? x_in : xb;
        const float* ec = (l == 0) ? ea_in : eab;
        hipMemsetAsync(agg, 0, (size_t)NN * DD * sizeof(float), stream);
        k_msg<<<1024, 256, 0, stream>>>(xc, ec, ei,
                                        msg_W + l * 128 * DD, msg_b + l * DD, agg);
        k_node<<<512, 256, 0, stream>>>(xc, agg, deg,
                                        agg_W + l * 128 * DD, agg_b + l * DD, xb);
        if (l < 2)  // layer-2 edge update is dead code (output depends on x only)
            k_eup<<<1024, 256, 0, stream>>>(xb, ec, ei,
                                            eup_W + l * 192 * DD, eup_b + l * DD, eab);
    }
    k_post<<<512, 256, 0, stream>>>(xb, pW1, pb1, pW2, pb2, out);
}

// Round 4
// 1379.982 us; speedup vs baseline: 3.3468x; 3.3468x over previous
//
#include <hip/hip_runtime.h>
#include <hip/hip_fp16.h>

#define NN 100000
#define NE 1000000
#define DD 64

typedef __attribute__((ext_vector_type(8)))  _Float16 half8;
typedef __attribute__((ext_vector_type(4)))  _Float16 half4_t;
typedef __attribute__((ext_vector_type(16))) float    f32x16;

// ---------------------------------------------------------------- deg count
__global__ __launch_bounds__(256) void k_count(const int* __restrict__ tgt,
                                               float* __restrict__ deg) {
    int i = blockIdx.x * blockDim.x + threadIdx.x;
    if (i < NE) atomicAdd(&deg[tgt[i]], 1.0f);
}

// ------------------------------------------------------------ convert x f16
__global__ __launch_bounds__(256) void k_cvtx(const float* __restrict__ src,
                                              _Float16* __restrict__ dst) {
    int i = blockIdx.x * 256 + threadIdx.x;   // NN*16 float4 groups
    if (i < NN * 16) {
        float4 v = ((const float4*)src)[i];
        half4_t o = { (_Float16)v.x, (_Float16)v.y, (_Float16)v.z, (_Float16)v.w };
        ((half4_t*)dst)[i] = o;
    }
}

// ------------------------------------------------------- convert weights f16
__global__ __launch_bounds__(256) void k_cvtw(
    const float* __restrict__ msgW, const float* __restrict__ aggW,
    const float* __restrict__ eupW,
    _Float16* __restrict__ msgW16, _Float16* __restrict__ aggW16,
    _Float16* __restrict__ eupW16)
{
    int i = blockIdx.x * 256 + threadIdx.x;
    if (i < 3 * 128 * 64) { msgW16[i] = (_Float16)msgW[i]; aggW16[i] = (_Float16)aggW[i]; }
    if (i < 3 * 192 * 64) eupW16[i] = (_Float16)eupW[i];
}

// ------------------------------------------------- message matvec + scatter
// 32 edges per wave-tile; A = gathered rows (K=128), B = weight frags in VGPR.
template<int EAF32>
__global__ __launch_bounds__(256) void k_msg(
    const _Float16* __restrict__ x, const void* __restrict__ ea_,
    const int* __restrict__ ei,
    const _Float16* __restrict__ W16, const float* __restrict__ bias,
    float* __restrict__ agg)
{
    __shared__ __attribute__((aligned(16))) char lds[4][32 * 256];
    __shared__ int sTn[4][32];
    const int lane = threadIdx.x & 63;
    const int wv   = threadIdx.x >> 6;
    const int hi   = lane >> 5;
    const int lr   = lane & 31;

    // B fragments: 8 k-steps x 2 col-halves.  B[k][n]: k = kk*16+hi*8+i, n = c*32+lr
    half8 Bf[8][2];
    for (int kk = 0; kk < 8; ++kk)
        for (int c = 0; c < 2; ++c) {
            half8 b;
#pragma unroll
            for (int i = 0; i < 8; ++i)
                b[i] = W16[(kk * 16 + hi * 8 + i) * 64 + c * 32 + lr];
            Bf[kk][c] = b;
        }
    const float bl0 = bias[lr], bl1 = bias[32 + lr];

    const int nw  = (gridDim.x * blockDim.x) >> 6;
    const int wid = (blockIdx.x * blockDim.x + threadIdx.x) >> 6;
    char* myl = lds[wv];

    for (int t = wid; t < NE / 32; t += nw) {
        const int e0 = t * 32;
        const int sn = ei[e0 + lr];
        const int tn = ei[NE + e0 + lr];
        if (lane < 32) sTn[wv][lr] = tn;

        // gather: 16 slots of 16B per row; iter j handles slot s = j*2+hi of row lr
#pragma unroll
        for (int j = 0; j < 8; ++j) {
            const int s = j * 2 + hi;
            half8 v;
            if (s < 8) {
                v = *(const half8*)(x + sn * 64 + (s & 7) * 8);
            } else {
                if (EAF32) {
                    const float* p = ((const float*)ea_) + (e0 + lr) * 64 + (s & 7) * 8;
                    float4 v0 = *(const float4*)p, v1 = *(const float4*)(p + 4);
                    v[0]=(_Float16)v0.x; v[1]=(_Float16)v0.y; v[2]=(_Float16)v0.z; v[3]=(_Float16)v0.w;
                    v[4]=(_Float16)v1.x; v[5]=(_Float16)v1.y; v[6]=(_Float16)v1.z; v[7]=(_Float16)v1.w;
                } else {
                    v = *(const half8*)((const _Float16*)ea_ + (e0 + lr) * 64 + (s & 7) * 8);
                }
            }
            *(half8*)(myl + lr * 256 + ((s ^ (lr & 7)) * 16)) = v;
        }

        f32x16 C0 = {}, C1 = {};
#pragma unroll
        for (int kk = 0; kk < 8; ++kk) {
            const int s0 = kk * 2 + hi;
            half8 a = *(const half8*)(myl + lr * 256 + ((s0 ^ (lr & 7)) * 16));
            C0 = __builtin_amdgcn_mfma_f32_32x32x16_f16(a, Bf[kk][0], C0, 0, 0, 0);
            C1 = __builtin_amdgcn_mfma_f32_32x32x16_f16(a, Bf[kk][1], C1, 0, 0, 0);
        }

        // scatter: C row = (r&3)+8*(r>>2)+4*hi, col = lr (+32)
#pragma unroll
        for (int r = 0; r < 16; ++r) {
            const int row = (r & 3) + 8 * (r >> 2) + 4 * hi;
            const int t2  = sTn[wv][row];
            const float m0 = fmaxf(C0[r] + bl0, 0.f);
            const float m1 = fmaxf(C1[r] + bl1, 0.f);
            atomicAdd(&agg[t2 * 64 + lr], m0);
            atomicAdd(&agg[t2 * 64 + 32 + lr], m1);
        }
    }
}

// ------------------------------------------------------------- node update
__global__ __launch_bounds__(256) void k_node(
    const _Float16* __restrict__ x, const float* __restrict__ agg,
    const float* __restrict__ deg,
    const _Float16* __restrict__ W16, const float* __restrict__ bias,
    _Float16* __restrict__ xout)
{
    __shared__ __attribute__((aligned(16))) char lds[4][32 * 256];
    const int lane = threadIdx.x & 63;
    const int wv   = threadIdx.x >> 6;
    const int hi   = lane >> 5;
    const int lr   = lane & 31;

    half8 Bf[8][2];
    for (int kk = 0; kk < 8; ++kk)
        for (int c = 0; c < 2; ++c) {
            half8 b;
#pragma unroll
            for (int i = 0; i < 8; ++i)
                b[i] = W16[(kk * 16 + hi * 8 + i) * 64 + c * 32 + lr];
            Bf[kk][c] = b;
        }
    const float bl0 = bias[lr], bl1 = bias[32 + lr];

    const int nw  = (gridDim.x * blockDim.x) >> 6;
    const int wid = (blockIdx.x * blockDim.x + threadIdx.x) >> 6;
    char* myl = lds[wv];

    for (int t = wid; t < NN / 32; t += nw) {
        const int n0 = t * 32;
        const float inv = 1.0f / fmaxf(deg[n0 + lr], 1.0f);

#pragma unroll
        for (int j = 0; j < 8; ++j) {
            const int s = j * 2 + hi;
            half8 v;
            if (s < 8) {
                const float* p = agg + (n0 + lr) * 64 + (s & 7) * 8;
                float4 v0 = *(const float4*)p, v1 = *(const float4*)(p + 4);
                v[0]=(_Float16)(v0.x*inv); v[1]=(_Float16)(v0.y*inv);
                v[2]=(_Float16)(v0.z*inv); v[3]=(_Float16)(v0.w*inv);
                v[4]=(_Float16)(v1.x*inv); v[5]=(_Float16)(v1.y*inv);
                v[6]=(_Float16)(v1.z*inv); v[7]=(_Float16)(v1.w*inv);
            } else {
                v = *(const half8*)(x + (n0 + lr) * 64 + (s & 7) * 8);
            }
            *(half8*)(myl + lr * 256 + ((s ^ (lr & 7)) * 16)) = v;
        }

        f32x16 C0 = {}, C1 = {};
#pragma unroll
        for (int kk = 0; kk < 8; ++kk) {
            const int s0 = kk * 2 + hi;
            half8 a = *(const half8*)(myl + lr * 256 + ((s0 ^ (lr & 7)) * 16));
            C0 = __builtin_amdgcn_mfma_f32_32x32x16_f16(a, Bf[kk][0], C0, 0, 0, 0);
            C1 = __builtin_amdgcn_mfma_f32_32x32x16_f16(a, Bf[kk][1], C1, 0, 0, 0);
        }

#pragma unroll
        for (int r = 0; r < 16; ++r) {
            const int row = (r & 3) + 8 * (r >> 2) + 4 * hi;
            float h0 = fmaxf(C0[r] + bl0, 0.f);
            float h1 = fmaxf(C1[r] + bl1, 0.f);
            float s2 = h0 * h0 + h1 * h1;
#pragma unroll
            for (int off = 16; off > 0; off >>= 1) s2 += __shfl_xor(s2, off);
            const float rn = 1.0f / fmaxf(sqrtf(s2), 1e-12f);
            const int n = n0 + row;
            xout[n * 64 + lr]      = (_Float16)(h0 * rn);
            xout[n * 64 + 32 + lr] = (_Float16)(h1 * rn);
        }
    }
}

// ------------------------------------------------------------- edge update
template<int EAF32>
__global__ __launch_bounds__(256) void k_eup(
    const _Float16* __restrict__ x, const void* __restrict__ ea_,
    const int* __restrict__ ei,
    const _Float16* __restrict__ W16, const float* __restrict__ bias,
    _Float16* __restrict__ eout)
{
    __shared__ __attribute__((aligned(16))) char lds[4][32 * 384];
    const int lane = threadIdx.x & 63;
    const int wv   = threadIdx.x >> 6;
    const int hi   = lane >> 5;
    const int lr   = lane & 31;

    half8 Bf[12][2];
    for (int kk = 0; kk < 12; ++kk)
        for (int c = 0; c < 2; ++c) {
            half8 b;
#pragma unroll
            for (int i = 0; i < 8; ++i)
                b[i] = W16[(kk * 16 + hi * 8 + i) * 64 + c * 32 + lr];
            Bf[kk][c] = b;
        }
    const float bl0 = bias[lr], bl1 = bias[32 + lr];

    const int nw  = (gridDim.x * blockDim.x) >> 6;
    const int wid = (blockIdx.x * blockDim.x + threadIdx.x) >> 6;
    char* myl = lds[wv];

    for (int t = wid; t < NE / 32; t += nw) {
        const int e0 = t * 32;
        const int sn = ei[e0 + lr];
        const int tn = ei[NE + e0 + lr];

        // 24 slots/row: sec0 = x[src], sec1 = x[tgt], sec2 = ea
#pragma unroll
        for (int j = 0; j < 12; ++j) {
            const int s = j * 2 + hi;
            half8 v;
            if (s < 8) {
                v = *(const half8*)(x + sn * 64 + (s & 7) * 8);
            } else if (s < 16) {
                v = *(const half8*)(x + tn * 64 + (s & 7) * 8);
            } else {
                if (EAF32) {
                    const float* p = ((const float*)ea_) + (e0 + lr) * 64 + (s & 7) * 8;
                    float4 v0 = *(const float4*)p, v1 = *(const float4*)(p + 4);
                    v[0]=(_Float16)v0.x; v[1]=(_Float16)v0.y; v[2]=(_Float16)v0.z; v[3]=(_Float16)v0.w;
                    v[4]=(_Float16)v1.x; v[5]=(_Float16)v1.y; v[6]=(_Float16)v1.z; v[7]=(_Float16)v1.w;
                } else {
                    v = *(const half8*)((const _Float16*)ea_ + (e0 + lr) * 64 + (s & 7) * 8);
                }
            }
            *(half8*)(myl + lr * 384 + ((s ^ (lr & 7)) * 16)) = v;
        }

        f32x16 C0 = {}, C1 = {};
#pragma unroll
        for (int kk = 0; kk < 12; ++kk) {
            const int s0 = kk * 2 + hi;
            half8 a = *(const half8*)(myl + lr * 384 + ((s0 ^ (lr & 7)) * 16));
            C0 = __builtin_amdgcn_mfma_f32_32x32x16_f16(a, Bf[kk][0], C0, 0, 0, 0);
            C1 = __builtin_amdgcn_mfma_f32_32x32x16_f16(a, Bf[kk][1], C1, 0, 0, 0);
        }

#pragma unroll
        for (int r = 0; r < 16; ++r) {
            const int row = (r & 3) + 8 * (r >> 2) + 4 * hi;
            const int e = e0 + row;
            eout[e * 64 + lr]      = (_Float16)fmaxf(C0[r] + bl0, 0.f);
            eout[e * 64 + 32 + lr] = (_Float16)fmaxf(C1[r] + bl1, 0.f);
        }
    }
}

// ---------------------------------------------------------------- post MLP
__global__ __launch_bounds__(256, 2) void k_post(
    const _Float16* __restrict__ x,
    const float* __restrict__ W1, const float* __restrict__ b1,
    const float* __restrict__ W2, const float* __restrict__ b2,
    float* __restrict__ out)
{
    __shared__ __attribute__((aligned(16))) float sIn[4][4][64];
    const int lane = threadIdx.x & 63;
    const int wv   = threadIdx.x >> 6;

    float w1[64], w2[64];
#pragma unroll
    for (int k = 0; k < 64; ++k) w1[k] = W1[k * DD + lane];
#pragma unroll
    for (int k = 0; k < 64; ++k) w2[k] = W2[k * DD + lane];
    const float bl1 = b1[lane];
    const float bl2 = b2[lane];

    const int wt    = (gridDim.x * blockDim.x) >> 6;
    const int wid   = (blockIdx.x * blockDim.x + threadIdx.x) >> 6;
    const int niter = (NN + wt * 4 - 1) / (wt * 4);

    for (int it = 0; it < niter; ++it) {
        const int n0 = (it * wt + wid) * 4;
#pragma unroll
        for (int s = 0; s < 4; ++s) {
            const int n = n0 + s;
            float vx = 0.f;
            if (n < NN) vx = (float)x[n * DD + lane];
            sIn[wv][s][lane] = vx;
        }
        __syncthreads();
#pragma unroll 1
        for (int s = 0; s < 4; ++s) {
            const int n = n0 + s;
            const float4* in4 = (const float4*)(&sIn[wv][s][0]);
            float a0 = 0.f, a1 = 0.f, a2 = 0.f, a3 = 0.f;
#pragma unroll
            for (int k = 0; k < 16; ++k) {
                const float4 v = in4[k];
                a0 = fmaf(v.x, w1[4 * k + 0], a0);
                a1 = fmaf(v.y, w1[4 * k + 1], a1);
                a2 = fmaf(v.z, w1[4 * k + 2], a2);
                a3 = fmaf(v.w, w1[4 * k + 3], a3);
            }
            const float h = fmaxf((a0 + a1) + (a2 + a3) + bl1, 0.f);
            float acc = bl2;
#pragma unroll
            for (int k = 0; k < 64; ++k) acc = fmaf(__shfl(h, k), w2[k], acc);
            if (n < NN) out[n * DD + lane] = acc;
        }
        __syncthreads();
    }
}

// --------------------------------------------------------------------------
extern "C" void kernel_launch(void* const* d_in, const int* in_sizes, int n_in,
                              void* d_out, int out_size, void* d_ws, size_t ws_size,
                              hipStream_t stream)
{
    const float* x_in  = (const float*)d_in[0];
    const float* ea_in = (const float*)d_in[1];
    const int*   ei    = (const int*)d_in[2];
    const float* msg_W = (const float*)d_in[3];
    const float* msg_b = (const float*)d_in[4];
    const float* agg_W = (const float*)d_in[5];
    const float* agg_b = (const float*)d_in[6];
    const float* eup_W = (const float*)d_in[7];
    const float* eup_b = (const float*)d_in[8];
    const float* pW1   = (const float*)d_in[9];
    const float* pb1   = (const float*)d_in[10];
    const float* pW2   = (const float*)d_in[11];
    const float* pb2   = (const float*)d_in[12];
    float* out = (float*)d_out;

    float*    deg = (float*)d_ws;              // 100352 f32
    float*    agg = deg + 100352;              // NN*64 f32
    _Float16* xb  = (_Float16*)(agg + NN * DD);        // NN*64 f16
    _Float16* eab = xb + NN * DD;              // NE*64 f16
    _Float16* mW16 = eab + (size_t)NE * DD;    // 3*128*64
    _Float16* aW16 = mW16 + 3 * 128 * 64;      // 3*128*64
    _Float16* eW16 = aW16 + 3 * 128 * 64;      // 3*192*64

    hipMemsetAsync(deg, 0, NN * sizeof(float), stream);
    k_count<<<(NE + 255) / 256, 256, 0, stream>>>(ei + NE, deg);
    k_cvtx<<<(NN * 16 + 255) / 256, 256, 0, stream>>>(x_in, xb);
    k_cvtw<<<(3 * 192 * 64 + 255) / 256, 256, 0, stream>>>(msg_W, agg_W, eup_W,
                                                           mW16, aW16, eW16);

    for (int l = 0; l < 3; ++l) {
        hipMemsetAsync(agg, 0, (size_t)NN * DD * sizeof(float), stream);
        if (l == 0)
            k_msg<1><<<1024, 256, 0, stream>>>(xb, ea_in, ei,
                                               mW16 + l * 128 * 64, msg_b + l * DD, agg);
        else
            k_msg<0><<<1024, 256, 0, stream>>>(xb, eab, ei,
                                               mW16 + l * 128 * 64, msg_b + l * DD, agg);
        k_node<<<256, 256, 0, stream>>>(xb, agg, deg,
                                        aW16 + l * 128 * 64, agg_b + l * DD, xb);
        if (l == 0)
            k_eup<1><<<1024, 256, 0, stream>>>(xb, ea_in, ei,
                                               eW16 + l * 192 * 64, eup_b + l * DD, eab);
        else if (l == 1)
            k_eup<0><<<1024, 256, 0, stream>>>(xb, eab, ei,
                                               eW16 + l * 192 * 64, eup_b + l * DD, eab);
        // layer-2 edge update is dead code
    }
    k_post<<<512, 256, 0, stream>>>(xb, pW1, pb1, pW2, pb2, out);
}

// Round 7
// 1125.026 us; speedup vs baseline: 4.1052x; 1.2266x over previous
//
#include <hip/hip_runtime.h>
#include <hip/hip_fp16.h>

#define NN 100000
#define NE 1000000
#define DD 64

typedef __attribute__((ext_vector_type(8)))  _Float16 half8;
typedef __attribute__((ext_vector_type(4)))  _Float16 half4_t;
typedef __attribute__((ext_vector_type(2)))  _Float16 half2_t;
typedef __attribute__((ext_vector_type(16))) float    f32x16;

// packed f16 atomic add (2 adjacent f16) — deterministic inline asm.
// gfx950 has global_atomic_pk_add_f16 (CDNA lineage since gfx90a).
__device__ __forceinline__ void pk_atomic_add(_Float16* p, float a, float b) {
    half2_t v = { (_Float16)a, (_Float16)b };
    asm volatile("global_atomic_pk_add_f16 %0, %1, off"
                 :: "v"(p), "v"(v) : "memory");
}

__device__ __forceinline__ half8 cvt8(const float4 a, const float4 b) {
    half8 v;
    v[0]=(_Float16)a.x; v[1]=(_Float16)a.y; v[2]=(_Float16)a.z; v[3]=(_Float16)a.w;
    v[4]=(_Float16)b.x; v[5]=(_Float16)b.y; v[6]=(_Float16)b.z; v[7]=(_Float16)b.w;
    return v;
}

// ---------------------------------------------------------------- deg count
__global__ __launch_bounds__(256) void k_count(const int* __restrict__ tgt,
                                               float* __restrict__ deg) {
    int i = blockIdx.x * blockDim.x + threadIdx.x;
    if (i < NE) atomicAdd(&deg[tgt[i]], 1.0f);
}

// ------------------------------------------------------------ convert x f16
__global__ __launch_bounds__(256) void k_cvtx(const float* __restrict__ src,
                                              _Float16* __restrict__ dst) {
    int i = blockIdx.x * 256 + threadIdx.x;   // NN*16 float4 groups
    if (i < NN * 16) {
        float4 v = ((const float4*)src)[i];
        half4_t o = { (_Float16)v.x, (_Float16)v.y, (_Float16)v.z, (_Float16)v.w };
        ((half4_t*)dst)[i] = o;
    }
}

// ------------------------------------------------------- convert weights f16
__global__ __launch_bounds__(256) void k_cvtw(
    const float* __restrict__ msgW, const float* __restrict__ aggW,
    const float* __restrict__ eupW,
    _Float16* __restrict__ msgW16, _Float16* __restrict__ aggW16,
    _Float16* __restrict__ eupW16)
{
    int i = blockIdx.x * 256 + threadIdx.x;
    if (i < 3 * 128 * 64) { msgW16[i] = (_Float16)msgW[i]; aggW16[i] = (_Float16)aggW[i]; }
    if (i < 3 * 192 * 64) eupW16[i] = (_Float16)eupW[i];
}

// ------------------------------------------------- message matvec + scatter
// 32 edges/wave-tile. A-frags gathered DIRECTLY from global (no LDS).
// B cols permuted even/odd: C0[r] = true col 2*lr, C1[r] = 2*lr+1 → pk atomics.
template<int EAF32>
__global__ __launch_bounds__(256) void k_msg(
    const _Float16* __restrict__ x, const void* __restrict__ ea_,
    const int* __restrict__ ei,
    const _Float16* __restrict__ W16, const float* __restrict__ bias,
    _Float16* __restrict__ agg)
{
    const int lane = threadIdx.x & 63;
    const int hi   = lane >> 5;
    const int lr   = lane & 31;

    half8 Bf[8][2];
    for (int kk = 0; kk < 8; ++kk)
        for (int c = 0; c < 2; ++c) {
            half8 b;
#pragma unroll
            for (int i = 0; i < 8; ++i)
                b[i] = W16[(kk * 16 + hi * 8 + i) * 64 + 2 * lr + c];
            Bf[kk][c] = b;
        }
    const float bl0 = bias[2 * lr], bl1 = bias[2 * lr + 1];

    const int nw  = (gridDim.x * blockDim.x) >> 6;
    const int wid = (blockIdx.x * blockDim.x + threadIdx.x) >> 6;

    for (int t = wid; t < NE / 32; t += nw) {
        const int e0 = t * 32;
        const int sn = ei[e0 + lr];
        const int tn = ei[NE + e0 + lr];

        half8 A[8];
#pragma unroll
        for (int kk = 0; kk < 8; ++kk) {
            if (kk < 4) {               // x[src] section, k = kk*16+hi*8
                A[kk] = *(const half8*)(x + (size_t)sn * 64 + kk * 16 + hi * 8);
            } else if (EAF32) {         // edge_attr section (fp32 input)
                const float* p = (const float*)ea_ + (size_t)(e0 + lr) * 64
                                 + (kk - 4) * 16 + hi * 8;
                A[kk] = cvt8(*(const float4*)p, *(const float4*)(p + 4));
            } else {                    // edge_attr section (f16 buffer)
                A[kk] = *(const half8*)((const _Float16*)ea_
                                        + (size_t)(e0 + lr) * 64 + (kk - 4) * 16 + hi * 8);
            }
        }

        f32x16 C0 = {}, C1 = {};
#pragma unroll
        for (int kk = 0; kk < 8; ++kk) {
            C0 = __builtin_amdgcn_mfma_f32_32x32x16_f16(A[kk], Bf[kk][0], C0, 0, 0, 0);
            C1 = __builtin_amdgcn_mfma_f32_32x32x16_f16(A[kk], Bf[kk][1], C1, 0, 0, 0);
        }

#pragma unroll
        for (int r = 0; r < 16; ++r) {
            const int row = (r & 3) + 8 * (r >> 2) + 4 * hi;
            const int t2  = __shfl(tn, row);
            pk_atomic_add(agg + (size_t)t2 * 64 + 2 * lr,
                          fmaxf(C0[r] + bl0, 0.f), fmaxf(C1[r] + bl1, 0.f));
        }
    }
}

// ------------------------------------------------------------- node update
// agg holds raw f16 sums. The deg-division applies ONLY to the agg section
// of the concatenation, so scale the agg A-fragments in-register pre-MFMA.
__global__ __launch_bounds__(256) void k_node(
    const _Float16* __restrict__ x, const _Float16* __restrict__ agg,
    const float* __restrict__ deg,
    const _Float16* __restrict__ W16, const float* __restrict__ bias,
    _Float16* __restrict__ xout)
{
    const int lane = threadIdx.x & 63;
    const int hi   = lane >> 5;
    const int lr   = lane & 31;

    half8 Bf[8][2];
    for (int kk = 0; kk < 8; ++kk)
        for (int c = 0; c < 2; ++c) {
            half8 b;
#pragma unroll
            for (int i = 0; i < 8; ++i)
                b[i] = W16[(kk * 16 + hi * 8 + i) * 64 + 2 * lr + c];
            Bf[kk][c] = b;
        }
    const float bl0 = bias[2 * lr], bl1 = bias[2 * lr + 1];

    const int nw  = (gridDim.x * blockDim.x) >> 6;
    const int wid = (blockIdx.x * blockDim.x + threadIdx.x) >> 6;

    for (int t = wid; t < NN / 32; t += nw) {
        const int n0  = t * 32;
        const float inv = 1.0f / fmaxf(deg[n0 + lr], 1.0f);
        const _Float16 ivh = (_Float16)inv;   // lane lr's own row scale

        half8 A[8];
#pragma unroll
        for (int kk = 0; kk < 8; ++kk) {
            if (kk < 4) { // agg section: scale raw sums by 1/deg (row-local)
                half8 a = *(const half8*)(agg + (size_t)(n0 + lr) * 64 + kk * 16 + hi * 8);
                A[kk] = a * ivh;
            } else {      // x section: unscaled
                A[kk] = *(const half8*)(x + (size_t)(n0 + lr) * 64 + (kk - 4) * 16 + hi * 8);
            }
        }

        f32x16 C0 = {}, C1 = {};
#pragma unroll
        for (int kk = 0; kk < 8; ++kk) {
            C0 = __builtin_amdgcn_mfma_f32_32x32x16_f16(A[kk], Bf[kk][0], C0, 0, 0, 0);
            C1 = __builtin_amdgcn_mfma_f32_32x32x16_f16(A[kk], Bf[kk][1], C1, 0, 0, 0);
        }

#pragma unroll
        for (int r = 0; r < 16; ++r) {
            const int row = (r & 3) + 8 * (r >> 2) + 4 * hi;
            float h0 = fmaxf(C0[r] + bl0, 0.f);
            float h1 = fmaxf(C1[r] + bl1, 0.f);
            float s2 = h0 * h0 + h1 * h1;
#pragma unroll
            for (int off = 16; off > 0; off >>= 1) s2 += __shfl_xor(s2, off);
            const float rn = 1.0f / fmaxf(sqrtf(s2), 1e-12f);
            half2_t o = { (_Float16)(h0 * rn), (_Float16)(h1 * rn) };
            *(half2_t*)(xout + (size_t)(n0 + row) * 64 + 2 * lr) = o;
        }
    }
}

// ------------------------------------------------------------- edge update
template<int EAF32>
__global__ __launch_bounds__(256) void k_eup(
    const _Float16* __restrict__ x, const void* __restrict__ ea_,
    const int* __restrict__ ei,
    const _Float16* __restrict__ W16, const float* __restrict__ bias,
    _Float16* __restrict__ eout)
{
    const int lane = threadIdx.x & 63;
    const int hi   = lane >> 5;
    const int lr   = lane & 31;

    half8 Bf[12][2];
    for (int kk = 0; kk < 12; ++kk)
        for (int c = 0; c < 2; ++c) {
            half8 b;
#pragma unroll
            for (int i = 0; i < 8; ++i)
                b[i] = W16[(kk * 16 + hi * 8 + i) * 64 + 2 * lr + c];
            Bf[kk][c] = b;
        }
    const float bl0 = bias[2 * lr], bl1 = bias[2 * lr + 1];

    const int nw  = (gridDim.x * blockDim.x) >> 6;
    const int wid = (blockIdx.x * blockDim.x + threadIdx.x) >> 6;

    for (int t = wid; t < NE / 32; t += nw) {
        const int e0 = t * 32;
        const int sn = ei[e0 + lr];
        const int tn = ei[NE + e0 + lr];

        half8 A[12];
#pragma unroll
        for (int kk = 0; kk < 12; ++kk) {
            if (kk < 4) {
                A[kk] = *(const half8*)(x + (size_t)sn * 64 + kk * 16 + hi * 8);
            } else if (kk < 8) {
                A[kk] = *(const half8*)(x + (size_t)tn * 64 + (kk - 4) * 16 + hi * 8);
            } else if (EAF32) {
                const float* p = (const float*)ea_ + (size_t)(e0 + lr) * 64
                                 + (kk - 8) * 16 + hi * 8;
                A[kk] = cvt8(*(const float4*)p, *(const float4*)(p + 4));
            } else {
                A[kk] = *(const half8*)((const _Float16*)ea_
                                        + (size_t)(e0 + lr) * 64 + (kk - 8) * 16 + hi * 8);
            }
        }

        f32x16 C0 = {}, C1 = {};
#pragma unroll
        for (int kk = 0; kk < 12; ++kk) {
            C0 = __builtin_amdgcn_mfma_f32_32x32x16_f16(A[kk], Bf[kk][0], C0, 0, 0, 0);
            C1 = __builtin_amdgcn_mfma_f32_32x32x16_f16(A[kk], Bf[kk][1], C1, 0, 0, 0);
        }

#pragma unroll
        for (int r = 0; r < 16; ++r) {
            const int row = (r & 3) + 8 * (r >> 2) + 4 * hi;
            const int e   = e0 + row;
            half2_t o = { (_Float16)fmaxf(C0[r] + bl0, 0.f),
                          (_Float16)fmaxf(C1[r] + bl1, 0.f) };
            *(half2_t*)(eout + (size_t)e * 64 + 2 * lr) = o;
        }
    }
}

// ---------------------------------------------------------------- post MLP
__global__ __launch_bounds__(256, 2) void k_post(
    const _Float16* __restrict__ x,
    const float* __restrict__ W1, const float* __restrict__ b1,
    const float* __restrict__ W2, const float* __restrict__ b2,
    float* __restrict__ out)
{
    __shared__ __attribute__((aligned(16))) float sIn[4][4][64];
    const int lane = threadIdx.x & 63;
    const int wv   = threadIdx.x >> 6;

    float w1[64], w2[64];
#pragma unroll
    for (int k = 0; k < 64; ++k) w1[k] = W1[k * DD + lane];
#pragma unroll
    for (int k = 0; k < 64; ++k) w2[k] = W2[k * DD + lane];
    const float bl1 = b1[lane];
    const float bl2 = b2[lane];

    const int wt    = (gridDim.x * blockDim.x) >> 6;
    const int wid   = (blockIdx.x * blockDim.x + threadIdx.x) >> 6;
    const int niter = (NN + wt * 4 - 1) / (wt * 4);

    for (int it = 0; it < niter; ++it) {
        const int n0 = (it * wt + wid) * 4;
#pragma unroll
        for (int s = 0; s < 4; ++s) {
            const int n = n0 + s;
            float vx = 0.f;
            if (n < NN) vx = (float)x[n * DD + lane];
            sIn[wv][s][lane] = vx;
        }
        __syncthreads();
#pragma unroll 1
        for (int s = 0; s < 4; ++s) {
            const int n = n0 + s;
            const float4* in4 = (const float4*)(&sIn[wv][s][0]);
            float a0 = 0.f, a1 = 0.f, a2 = 0.f, a3 = 0.f;
#pragma unroll
            for (int k = 0; k < 16; ++k) {
                const float4 v = in4[k];
                a0 = fmaf(v.x, w1[4 * k + 0], a0);
                a1 = fmaf(v.y, w1[4 * k + 1], a1);
                a2 = fmaf(v.z, w1[4 * k + 2], a2);
                a3 = fmaf(v.w, w1[4 * k + 3], a3);
            }
            const float h = fmaxf((a0 + a1) + (a2 + a3) + bl1, 0.f);
            float acc = bl2;
#pragma unroll
            for (int k = 0; k < 64; ++k) acc = fmaf(__shfl(h, k), w2[k], acc);
            if (n < NN) out[n * DD + lane] = acc;
        }
        __syncthreads();
    }
}

// --------------------------------------------------------------------------
extern "C" void kernel_launch(void* const* d_in, const int* in_sizes, int n_in,
                              void* d_out, int out_size, void* d_ws, size_t ws_size,
                              hipStream_t stream)
{
    const float* x_in  = (const float*)d_in[0];
    const float* ea_in = (const float*)d_in[1];
    const int*   ei    = (const int*)d_in[2];
    const float* msg_W = (const float*)d_in[3];
    const float* msg_b = (const float*)d_in[4];
    const float* agg_W = (const float*)d_in[5];
    const float* agg_b = (const float*)d_in[6];
    const float* eup_W = (const float*)d_in[7];
    const float* eup_b = (const float*)d_in[8];
    const float* pW1   = (const float*)d_in[9];
    const float* pb1   = (const float*)d_in[10];
    const float* pW2   = (const float*)d_in[11];
    const float* pb2   = (const float*)d_in[12];
    float* out = (float*)d_out;

    float*    deg  = (float*)d_ws;                       // 100352 f32
    _Float16* agg  = (_Float16*)(deg + 100352);          // NN*64 f16
    _Float16* xb   = agg + (size_t)NN * DD;              // NN*64 f16
    _Float16* eab  = xb + (size_t)NN * DD;               // NE*64 f16
    _Float16* mW16 = eab + (size_t)NE * DD;              // 3*128*64
    _Float16* aW16 = mW16 + 3 * 128 * 64;
    _Float16* eW16 = aW16 + 3 * 128 * 64;

    hipMemsetAsync(deg, 0, NN * sizeof(float), stream);
    k_count<<<(NE + 255) / 256, 256, 0, stream>>>(ei + NE, deg);
    k_cvtx<<<(NN * 16 + 255) / 256, 256, 0, stream>>>(x_in, xb);
    k_cvtw<<<(3 * 192 * 64 + 255) / 256, 256, 0, stream>>>(msg_W, agg_W, eup_W,
                                                           mW16, aW16, eW16);

    for (int l = 0; l < 3; ++l) {
        hipMemsetAsync(agg, 0, (size_t)NN * DD * sizeof(_Float16), stream);
        if (l == 0)
            k_msg<1><<<2048, 256, 0, stream>>>(xb, ea_in, ei,
                                               mW16 + l * 128 * 64, msg_b + l * DD, agg);
        else
            k_msg<0><<<2048, 256, 0, stream>>>(xb, eab, ei,
                                               mW16 + l * 128 * 64, msg_b + l * DD, agg);
        k_node<<<1024, 256, 0, stream>>>(xb, agg, deg,
                                         aW16 + l * 128 * 64, agg_b + l * DD, xb);
        if (l == 0)
            k_eup<1><<<2048, 256, 0, stream>>>(xb, ea_in, ei,
                                               eW16 + l * 192 * 64, eup_b + l * DD, eab);
        else if (l == 1)
            k_eup<0><<<2048, 256, 0, stream>>>(xb, eab, ei,
                                               eW16 + l * 192 * 64, eup_b + l * DD, eab);
        // layer-2 edge update is dead code (output depends only on x)
    }
    k_post<<<512, 256, 0, stream>>>(xb, pW1, pb1, pW2, pb2, out);
}

// Round 9
// 984.300 us; speedup vs baseline: 4.6922x; 1.1430x over previous
//
#include <hip/hip_runtime.h>
#include <hip/hip_fp16.h>

#define NN 100000
#define NE 1000000
#define DD 64

typedef __attribute__((ext_vector_type(8)))  _Float16 half8;
typedef __attribute__((ext_vector_type(4)))  _Float16 half4_t;
typedef __attribute__((ext_vector_type(2)))  _Float16 half2_t;
typedef __attribute__((ext_vector_type(16))) float    f32x16;

// packed f16 atomic add (2 adjacent f16) — verified round 7 (absmax 2e-3).
__device__ __forceinline__ void pk_atomic_add(_Float16* p, float a, float b) {
    half2_t v = { (_Float16)a, (_Float16)b };
    asm volatile("global_atomic_pk_add_f16 %0, %1, off"
                 :: "v"(p), "v"(v) : "memory");
}

__device__ __forceinline__ half8 cvt8(const float4 a, const float4 b) {
    half8 v;
    v[0]=(_Float16)a.x; v[1]=(_Float16)a.y; v[2]=(_Float16)a.z; v[3]=(_Float16)a.w;
    v[4]=(_Float16)b.x; v[5]=(_Float16)b.y; v[6]=(_Float16)b.z; v[7]=(_Float16)b.w;
    return v;
}

// ---------------------------------------------------------------- deg count
__global__ __launch_bounds__(256) void k_count(const int* __restrict__ tgt,
                                               float* __restrict__ deg) {
    int i = blockIdx.x * blockDim.x + threadIdx.x;
    if (i < NE) atomicAdd(&deg[tgt[i]], 1.0f);
}

// ------------------------------------------------------------ convert x f16
__global__ __launch_bounds__(256) void k_cvtx(const float* __restrict__ src,
                                              _Float16* __restrict__ dst) {
    int i = blockIdx.x * 256 + threadIdx.x;
    if (i < NN * 16) {
        float4 v = ((const float4*)src)[i];
        half4_t o = { (_Float16)v.x, (_Float16)v.y, (_Float16)v.z, (_Float16)v.w };
        ((half4_t*)dst)[i] = o;
    }
}

// ------------------------------------------------------- convert weights f16
__global__ __launch_bounds__(256) void k_cvtw(
    const float* __restrict__ msgW, const float* __restrict__ aggW,
    const float* __restrict__ eupW,
    _Float16* __restrict__ msgW16, _Float16* __restrict__ aggW16,
    _Float16* __restrict__ eupW16)
{
    int i = blockIdx.x * 256 + threadIdx.x;
    if (i < 3 * 128 * 64) { msgW16[i] = (_Float16)msgW[i]; aggW16[i] = (_Float16)aggW[i]; }
    if (i < 3 * 192 * 64) eupW16[i] = (_Float16)eupW[i];
}

// ------------------------------------------------- message matvec + scatter
// (layer 0 only) B frags in VGPR, direct global gathers, pk-f16 atomics.
template<int EAF32>
__global__ __launch_bounds__(256) void k_msg(
    const _Float16* __restrict__ x, const void* __restrict__ ea_,
    const int* __restrict__ ei,
    const _Float16* __restrict__ W16, const float* __restrict__ bias,
    _Float16* __restrict__ agg)
{
    const int lane = threadIdx.x & 63;
    const int hi   = lane >> 5;
    const int lr   = lane & 31;

    half8 Bf[8][2];
    for (int kk = 0; kk < 8; ++kk)
        for (int c = 0; c < 2; ++c) {
            half8 b;
#pragma unroll
            for (int i = 0; i < 8; ++i)
                b[i] = W16[(kk * 16 + hi * 8 + i) * 64 + 2 * lr + c];
            Bf[kk][c] = b;
        }
    const float bl0 = bias[2 * lr], bl1 = bias[2 * lr + 1];

    const int nw  = (gridDim.x * blockDim.x) >> 6;
    const int wid = (blockIdx.x * blockDim.x + threadIdx.x) >> 6;

    for (int t = wid; t < NE / 32; t += nw) {
        const int e0 = t * 32;
        const int sn = ei[e0 + lr];
        const int tn = ei[NE + e0 + lr];

        half8 A[8];
#pragma unroll
        for (int kk = 0; kk < 8; ++kk) {
            if (kk < 4) {
                A[kk] = *(const half8*)(x + (size_t)sn * 64 + kk * 16 + hi * 8);
            } else if (EAF32) {
                const float* p = (const float*)ea_ + (size_t)(e0 + lr) * 64
                                 + (kk - 4) * 16 + hi * 8;
                A[kk] = cvt8(*(const float4*)p, *(const float4*)(p + 4));
            } else {
                A[kk] = *(const half8*)((const _Float16*)ea_
                                        + (size_t)(e0 + lr) * 64 + (kk - 4) * 16 + hi * 8);
            }
        }

        f32x16 C0 = {}, C1 = {};
#pragma unroll
        for (int kk = 0; kk < 8; ++kk) {
            C0 = __builtin_amdgcn_mfma_f32_32x32x16_f16(A[kk], Bf[kk][0], C0, 0, 0, 0);
            C1 = __builtin_amdgcn_mfma_f32_32x32x16_f16(A[kk], Bf[kk][1], C1, 0, 0, 0);
        }

#pragma unroll
        for (int r = 0; r < 16; ++r) {
            const int row = (r & 3) + 8 * (r >> 2) + 4 * hi;
            const int t2  = __shfl(tn, row);
            pk_atomic_add(agg + (size_t)t2 * 64 + 2 * lr,
                          fmaxf(C0[r] + bl0, 0.f), fmaxf(C1[r] + bl1, 0.f));
        }
    }
}

// --------------------------------------- FUSED edge-update + next-layer msg
// ea_next = relu(eW^T cat(x[s],x[t],ea) + eb)   (optionally stored)
// m       = relu(mW^T cat(x[s],ea_next) + mb)  → pk-atomic scatter into agg
// Weights staged in LDS (frag-permuted); ea_next redistributed C→A layout
// via 4KB/wave XOR-swizzled LDS transpose (wave-private, no barriers).
template<int EAF32, int WRITE_EA>
__global__ __launch_bounds__(256) void k_eupmsg(
    const _Float16* __restrict__ x, const void* __restrict__ ea_,
    const int* __restrict__ ei,
    const _Float16* __restrict__ eW, const float* __restrict__ eb,
    const _Float16* __restrict__ mW, const float* __restrict__ mb,
    _Float16* __restrict__ eaout, _Float16* __restrict__ agg)
{
    // B frags: slot f = kk*2+c holds 64 lanes × half8 (1024 B)
    __shared__ __attribute__((aligned(16))) _Float16 sBe[24 * 512]; // 24 KB
    __shared__ __attribute__((aligned(16))) _Float16 sBm[16 * 512]; // 16 KB
    __shared__ __attribute__((aligned(16))) _Float16 sT[4][32 * 64]; // 4KB/wave

    const int lane = threadIdx.x & 63;
    const int wv   = threadIdx.x >> 6;
    const int hi   = lane >> 5;
    const int lr   = lane & 31;

    // stage weight fragments (one-time, W is L2-resident)
    for (int f = wv; f < 24; f += 4) {
        const int kk = f >> 1, c = f & 1;
        half8 b;
#pragma unroll
        for (int i = 0; i < 8; ++i)
            b[i] = eW[(kk * 16 + hi * 8 + i) * 64 + 2 * lr + c];
        *(half8*)(sBe + f * 512 + lane * 8) = b;
    }
    for (int f = wv; f < 16; f += 4) {
        const int kk = f >> 1, c = f & 1;
        half8 b;
#pragma unroll
        for (int i = 0; i < 8; ++i)
            b[i] = mW[(kk * 16 + hi * 8 + i) * 64 + 2 * lr + c];
        *(half8*)(sBm + f * 512 + lane * 8) = b;
    }
    __syncthreads();

    const float ebl0 = eb[2 * lr], ebl1 = eb[2 * lr + 1];
    const float mbl0 = mb[2 * lr], mbl1 = mb[2 * lr + 1];

    char* myT = (char*)(&sT[wv][0]);
    const int nw  = (gridDim.x * blockDim.x) >> 6;
    const int wid = (blockIdx.x * blockDim.x + threadIdx.x) >> 6;

    for (int t = wid; t < NE / 32; t += nw) {
        const int e0 = t * 32;
        const int sn = ei[e0 + lr];
        const int tn = ei[NE + e0 + lr];

        half8 As[4], At[4], Ae[4];
#pragma unroll
        for (int kk = 0; kk < 4; ++kk) {
            As[kk] = *(const half8*)(x + (size_t)sn * 64 + kk * 16 + hi * 8);
            At[kk] = *(const half8*)(x + (size_t)tn * 64 + kk * 16 + hi * 8);
            if (EAF32) {
                const float* p = (const float*)ea_ + (size_t)(e0 + lr) * 64
                                 + kk * 16 + hi * 8;
                Ae[kk] = cvt8(*(const float4*)p, *(const float4*)(p + 4));
            } else {
                Ae[kk] = *(const half8*)((const _Float16*)ea_
                                         + (size_t)(e0 + lr) * 64 + kk * 16 + hi * 8);
            }
        }

        // ---- edge-update MFMA (K = 192)
        f32x16 C0 = {}, C1 = {};
#pragma unroll
        for (int kk = 0; kk < 12; ++kk) {
            half8 a = (kk < 4) ? As[kk] : (kk < 8) ? At[kk - 4] : Ae[kk - 8];
            half8 b0 = *(const half8*)(sBe + (kk * 2 + 0) * 512 + lane * 8);
            half8 b1 = *(const half8*)(sBe + (kk * 2 + 1) * 512 + lane * 8);
            C0 = __builtin_amdgcn_mfma_f32_32x32x16_f16(a, b0, C0, 0, 0, 0);
            C1 = __builtin_amdgcn_mfma_f32_32x32x16_f16(a, b1, C1, 0, 0, 0);
        }

        // epilogue: relu+bias → ea_next; store + transpose into LDS
#pragma unroll
        for (int r = 0; r < 16; ++r) {
            const int row = (r & 3) + 8 * (r >> 2) + 4 * hi;
            half2_t o = { (_Float16)fmaxf(C0[r] + ebl0, 0.f),
                          (_Float16)fmaxf(C1[r] + ebl1, 0.f) };
            if (WRITE_EA)
                *(half2_t*)(eaout + (size_t)(e0 + row) * 64 + 2 * lr) = o;
            *(half2_t*)(myT + row * 128 + ((4 * lr) ^ ((row & 7) << 4))) = o;
        }
        // read back in A-frag layout (same-wave ds dependency → lgkm wait)
        half8 Ap[4];
#pragma unroll
        for (int kk2 = 0; kk2 < 4; ++kk2) {
            const int boff = kk2 * 32 + hi * 16;
            Ap[kk2] = *(const half8*)(myT + lr * 128 + (boff ^ ((lr & 7) << 4)));
        }

        // ---- next-layer message MFMA (K = 128) + scatter
        f32x16 D0 = {}, D1 = {};
#pragma unroll
        for (int kk = 0; kk < 8; ++kk) {
            half8 a = (kk < 4) ? As[kk] : Ap[kk - 4];
            half8 b0 = *(const half8*)(sBm + (kk * 2 + 0) * 512 + lane * 8);
            half8 b1 = *(const half8*)(sBm + (kk * 2 + 1) * 512 + lane * 8);
            D0 = __builtin_amdgcn_mfma_f32_32x32x16_f16(a, b0, D0, 0, 0, 0);
            D1 = __builtin_amdgcn_mfma_f32_32x32x16_f16(a, b1, D1, 0, 0, 0);
        }
#pragma unroll
        for (int r = 0; r < 16; ++r) {
            const int row = (r & 3) + 8 * (r >> 2) + 4 * hi;
            const int t2  = __shfl(tn, row);
            pk_atomic_add(agg + (size_t)t2 * 64 + 2 * lr,
                          fmaxf(D0[r] + mbl0, 0.f), fmaxf(D1[r] + mbl1, 0.f));
        }
    }
}

// ------------------------------------------------------------- node update
__global__ __launch_bounds__(256) void k_node(
    const _Float16* __restrict__ x, const _Float16* __restrict__ agg,
    const float* __restrict__ deg,
    const _Float16* __restrict__ W16, const float* __restrict__ bias,
    _Float16* __restrict__ xout)
{
    const int lane = threadIdx.x & 63;
    const int hi   = lane >> 5;
    const int lr   = lane & 31;

    half8 Bf[8][2];
    for (int kk = 0; kk < 8; ++kk)
        for (int c = 0; c < 2; ++c) {
            half8 b;
#pragma unroll
            for (int i = 0; i < 8; ++i)
                b[i] = W16[(kk * 16 + hi * 8 + i) * 64 + 2 * lr + c];
            Bf[kk][c] = b;
        }
    const float bl0 = bias[2 * lr], bl1 = bias[2 * lr + 1];

    const int nw  = (gridDim.x * blockDim.x) >> 6;
    const int wid = (blockIdx.x * blockDim.x + threadIdx.x) >> 6;

    for (int t = wid; t < NN / 32; t += nw) {
        const int n0  = t * 32;
        const float inv = 1.0f / fmaxf(deg[n0 + lr], 1.0f);
        const _Float16 ivh = (_Float16)inv;

        half8 A[8];
#pragma unroll
        for (int kk = 0; kk < 8; ++kk) {
            if (kk < 4) {
                half8 a = *(const half8*)(agg + (size_t)(n0 + lr) * 64 + kk * 16 + hi * 8);
                A[kk] = a * ivh;
            } else {
                A[kk] = *(const half8*)(x + (size_t)(n0 + lr) * 64 + (kk - 4) * 16 + hi * 8);
            }
        }

        f32x16 C0 = {}, C1 = {};
#pragma unroll
        for (int kk = 0; kk < 8; ++kk) {
            C0 = __builtin_amdgcn_mfma_f32_32x32x16_f16(A[kk], Bf[kk][0], C0, 0, 0, 0);
            C1 = __builtin_amdgcn_mfma_f32_32x32x16_f16(A[kk], Bf[kk][1], C1, 0, 0, 0);
        }

#pragma unroll
        for (int r = 0; r < 16; ++r) {
            const int row = (r & 3) + 8 * (r >> 2) + 4 * hi;
            float h0 = fmaxf(C0[r] + bl0, 0.f);
            float h1 = fmaxf(C1[r] + bl1, 0.f);
            float s2 = h0 * h0 + h1 * h1;
#pragma unroll
            for (int off = 16; off > 0; off >>= 1) s2 += __shfl_xor(s2, off);
            const float rn = 1.0f / fmaxf(sqrtf(s2), 1e-12f);
            half2_t o = { (_Float16)(h0 * rn), (_Float16)(h1 * rn) };
            *(half2_t*)(xout + (size_t)(n0 + row) * 64 + 2 * lr) = o;
        }
    }
}

// ---------------------------------------------------------------- post MLP
__global__ __launch_bounds__(256, 2) void k_post(
    const _Float16* __restrict__ x,
    const float* __restrict__ W1, const float* __restrict__ b1,
    const float* __restrict__ W2, const float* __restrict__ b2,
    float* __restrict__ out)
{
    __shared__ __attribute__((aligned(16))) float sIn[4][4][64];
    const int lane = threadIdx.x & 63;
    const int wv   = threadIdx.x >> 6;

    float w1[64], w2[64];
#pragma unroll
    for (int k = 0; k < 64; ++k) w1[k] = W1[k * DD + lane];
#pragma unroll
    for (int k = 0; k < 64; ++k) w2[k] = W2[k * DD + lane];
    const float bl1 = b1[lane];
    const float bl2 = b2[lane];

    const int wt    = (gridDim.x * blockDim.x) >> 6;
    const int wid   = (blockIdx.x * blockDim.x + threadIdx.x) >> 6;
    const int niter = (NN + wt * 4 - 1) / (wt * 4);

    for (int it = 0; it < niter; ++it) {
        const int n0 = (it * wt + wid) * 4;
#pragma unroll
        for (int s = 0; s < 4; ++s) {
            const int n = n0 + s;
            float vx = 0.f;
            if (n < NN) vx = (float)x[n * DD + lane];
            sIn[wv][s][lane] = vx;
        }
        __syncthreads();
#pragma unroll 1
        for (int s = 0; s < 4; ++s) {
            const int n = n0 + s;
            const float4* in4 = (const float4*)(&sIn[wv][s][0]);
            float a0 = 0.f, a1 = 0.f, a2 = 0.f, a3 = 0.f;
#pragma unroll
            for (int k = 0; k < 16; ++k) {
                const float4 v = in4[k];
                a0 = fmaf(v.x, w1[4 * k + 0], a0);
                a1 = fmaf(v.y, w1[4 * k + 1], a1);
                a2 = fmaf(v.z, w1[4 * k + 2], a2);
                a3 = fmaf(v.w, w1[4 * k + 3], a3);
            }
            const float h = fmaxf((a0 + a1) + (a2 + a3) + bl1, 0.f);
            float acc = bl2;
#pragma unroll
            for (int k = 0; k < 64; ++k) acc = fmaf(__shfl(h, k), w2[k], acc);
            if (n < NN) out[n * DD + lane] = acc;
        }
        __syncthreads();
    }
}

// --------------------------------------------------------------------------
extern "C" void kernel_launch(void* const* d_in, const int* in_sizes, int n_in,
                              void* d_out, int out_size, void* d_ws, size_t ws_size,
                              hipStream_t stream)
{
    const float* x_in  = (const float*)d_in[0];
    const float* ea_in = (const float*)d_in[1];
    const int*   ei    = (const int*)d_in[2];
    const float* msg_W = (const float*)d_in[3];
    const float* msg_b = (const float*)d_in[4];
    const float* agg_W = (const float*)d_in[5];
    const float* agg_b = (const float*)d_in[6];
    const float* eup_W = (const float*)d_in[7];
    const float* eup_b = (const float*)d_in[8];
    const float* pW1   = (const float*)d_in[9];
    const float* pb1   = (const float*)d_in[10];
    const float* pW2   = (const float*)d_in[11];
    const float* pb2   = (const float*)d_in[12];
    float* out = (float*)d_out;

    float*    deg  = (float*)d_ws;                       // 100352 f32
    _Float16* agg  = (_Float16*)(deg + 100352);          // NN*64 f16
    _Float16* xb   = agg + (size_t)NN * DD;              // NN*64 f16
    _Float16* eab  = xb + (size_t)NN * DD;               // NE*64 f16
    _Float16* mW16 = eab + (size_t)NE * DD;              // 3*128*64
    _Float16* aW16 = mW16 + 3 * 128 * 64;
    _Float16* eW16 = aW16 + 3 * 128 * 64;

    hipMemsetAsync(deg, 0, NN * sizeof(float), stream);
    k_count<<<(NE + 255) / 256, 256, 0, stream>>>(ei + NE, deg);
    k_cvtx<<<(NN * 16 + 255) / 256, 256, 0, stream>>>(x_in, xb);
    k_cvtw<<<(3 * 192 * 64 + 255) / 256, 256, 0, stream>>>(msg_W, agg_W, eup_W,
                                                           mW16, aW16, eW16);

    // ---- layer 0 message + node
    hipMemsetAsync(agg, 0, (size_t)NN * DD * sizeof(_Float16), stream);
    k_msg<1><<<2048, 256, 0, stream>>>(xb, ea_in, ei, mW16, msg_b, agg);
    k_node<<<1024, 256, 0, stream>>>(xb, agg, deg, aW16, agg_b, xb);

    // ---- fused eup0 + msg1 (writes ea1, scatters layer-1 messages)
    hipMemsetAsync(agg, 0, (size_t)NN * DD * sizeof(_Float16), stream);
    k_eupmsg<1, 1><<<512, 256, 0, stream>>>(
        xb, ea_in, ei,
        eW16, eup_b,                       // eup layer 0
        mW16 + 1 * 128 * 64, msg_b + DD,   // msg layer 1
        eab, agg);
    k_node<<<1024, 256, 0, stream>>>(xb, agg, deg,
                                     aW16 + 1 * 128 * 64, agg_b + DD, xb);

    // ---- fused eup1 + msg2 (ea2 stays in registers/LDS; never stored)
    hipMemsetAsync(agg, 0, (size_t)NN * DD * sizeof(_Float16), stream);
    k_eupmsg<0, 0><<<512, 256, 0, stream>>>(
        xb, eab, ei,
        eW16 + 1 * 192 * 64, eup_b + DD,   // eup layer 1
        mW16 + 2 * 128 * 64, msg_b + 2 * DD, // msg layer 2
        nullptr, agg);
    k_node<<<1024, 256, 0, stream>>>(xb, agg, deg,
                                     aW16 + 2 * 128 * 64, agg_b + 2 * DD, xb);

    k_post<<<512, 256, 0, stream>>>(xb, pW1, pb1, pW2, pb2, out);
}